// Round 2
// baseline (1829.235 us; speedup 1.0000x reference)
//
#include <hip/hip_runtime.h>
#include <hip/hip_bf16.h>

// ---------- types ----------
typedef __attribute__((ext_vector_type(8))) short bf16x8;   // 8 bf16 in 4 VGPRs
typedef __attribute__((ext_vector_type(4))) float f32x4;

#define MFMA_BF16(a, b, c) __builtin_amdgcn_mfma_f32_16x16x32_bf16((a), (b), (c), 0, 0, 0)

static __device__ __forceinline__ unsigned short f2bf(float f) {
  unsigned int u = __builtin_bit_cast(unsigned int, f);
  u += 0x7FFF + ((u >> 16) & 1);   // RNE
  return (unsigned short)(u >> 16);
}

// ---------- weight layout in d_ws (bf16 elements), FRAGMENT-ORDERED ----------
// Each 512-elem (1KB) chunk is one MFMA B-fragment: elem = lane*8 + j holds
// W[nb*16 + (lane&15)][ks*32 + (lane>>4)*8 + j]. Chunk index = ks*NB + nb.
enum : int {
  OFF_W0  = 0,        // NB=16 KS=2   (K 63 -> 64)
  OFF_W1  = 16384,    // NB=16 KS=8
  OFF_W2  = 81920,
  OFF_W3  = 147456,
  OFF_W4  = 212992,   // NB=16 KS=10  (K 319 -> 320)
  OFF_W5  = 294912,
  OFF_W6  = 360448,
  OFF_W7  = 425984,
  OFF_WF  = 491520,
  OFF_WC1 = 557056,   // NB=8  KS=9   (K 283 -> 288)
  OFF_WS  = 593920,   // NB=1  KS=8   (1 row -> 16)
  OFF_WC2 = 598016,   // NB=1  KS=4   (3 rows -> 16)
  W_TOTAL = 600064
};

struct Seg { const float* src; int rows_src, kin, nb, ks, off; };
struct SegArgs { Seg s[12]; };

__global__ void convert_weights(SegArgs args, unsigned short* __restrict__ dst) {
  int idx = blockIdx.x * 256 + threadIdx.x;
  #pragma unroll
  for (int i = 0; i < 12; i++) {
    const Seg sg = args.s[i];
    const int sz = sg.nb * sg.ks * 512;
    if (idx < sz) {
      const int f = idx >> 9, rm = idx & 511;
      const int lane = rm >> 3, j = rm & 7;
      const int ks = f / sg.nb, nb = f - ks * sg.nb;
      const int n = nb * 16 + (lane & 15);
      const int k = ks * 32 + ((lane >> 4) << 3) + j;
      float v = (n < sg.rows_src && k < sg.kin) ? sg.src[n * sg.kin + k] : 0.0f;
      dst[sg.off + idx] = f2bf(v);
      return;
    }
    idx -= sz;
  }
}

// ---------- GEMM helpers ----------
// MFMA 16x16x32 bf16 layouts (verified m89):
//   A[m][k]: m = lane&15, k = (lane>>4)*8 + j
//   B[k][n]: n = lane&15, k = (lane>>4)*8 + j
//   D[m][n]: n = lane&15, m = (lane>>4)*4 + reg
// LDS activation buffers are XOR-swizzled: byte ^= (row&7)<<4 (T2, bank-conflict-free).

template<int MF, int NF>
static __device__ __forceinline__ void zero_acc(f32x4 (&acc)[MF][NF]) {
  #pragma unroll
  for (int mi = 0; mi < MF; mi++)
    #pragma unroll
    for (int nf = 0; nf < NF; nf++)
      acc[mi][nf] = (f32x4){0.f, 0.f, 0.f, 0.f};
}

template<int MF, int NF, int KS, int NB, int ASTRIDE>
static __device__ __forceinline__ void gemm_frag(
    f32x4 (&acc)[MF][NF],
    const unsigned short* __restrict__ aLds, int mBase,
    const unsigned short* __restrict__ wseg, int nbBase, int ksOff)
{
  const int lane = threadIdx.x & 63;
  const int lr   = lane & 15;
  const int lq8  = (lane >> 4) * 8;
  #pragma unroll
  for (int ks = 0; ks < KS; ks++) {
    bf16x8 a[MF], b[NF];
    #pragma unroll
    for (int nf = 0; nf < NF; nf++)
      b[nf] = *(const bf16x8*)(wseg + (((ksOff + ks) * NB + nbBase + nf) << 9) + lane * 8);
    #pragma unroll
    for (int mi = 0; mi < MF; mi++) {
      const int row = mBase + mi * 16 + lr;
      const int col = ks * 32 + lq8;
      a[mi] = *(const bf16x8*)((const char*)aLds +
                (((row * ASTRIDE + col) << 1) ^ ((row & 7) << 4)));
    }
    #pragma unroll
    for (int mi = 0; mi < MF; mi++)
      #pragma unroll
      for (int nf = 0; nf < NF; nf++)
        acc[mi][nf] = MFMA_BF16(a[mi], b[nf], acc[mi][nf]);
  }
}

template<int MF, int NF, bool RELU, int ASTRIDE>
static __device__ __forceinline__ void store_act(
    const f32x4 (&acc)[MF][NF], const float* __restrict__ bias, int nBase,
    unsigned short* __restrict__ lds)
{
  const int lane = threadIdx.x & 63;
  const int lr   = lane & 15;
  const int lq4  = (lane >> 4) * 4;
  #pragma unroll
  for (int nf = 0; nf < NF; nf++) {
    const int n = nBase + nf * 16 + lr;
    const float bv = bias[n];
    #pragma unroll
    for (int mi = 0; mi < MF; mi++) {
      #pragma unroll
      for (int r = 0; r < 4; r++) {
        float v = acc[mi][nf][r] + bv;
        if (RELU) v = fmaxf(v, 0.0f);
        const int row = mi * 16 + lq4 + r;
        *(unsigned short*)((char*)lds +
            (((row * ASTRIDE + n) << 1) ^ ((row & 7) << 4))) = f2bf(v);
      }
    }
  }
}

// ---------- fused NeRF kernel: 64 rows / block, 4 waves, in-place act ----------
__global__ __launch_bounds__(256, 4) void nerf_main(
    const float* __restrict__ enc_pos, const float* __restrict__ enc_dir,
    const unsigned short* __restrict__ Wt,
    const float* __restrict__ b0, const float* __restrict__ b1,
    const float* __restrict__ b2, const float* __restrict__ b3,
    const float* __restrict__ b4, const float* __restrict__ b5,
    const float* __restrict__ b6, const float* __restrict__ b7,
    const float* __restrict__ bfb, const float* __restrict__ bsb,
    const float* __restrict__ bc1, const float* __restrict__ bc2,
    float* __restrict__ out)
{
  __shared__ __align__(16) unsigned short act[64 * 256];   // 32 KB, swizzled
  __shared__ __align__(16) unsigned short posb[64 * 64];   // 8 KB, swizzled

  const int tid  = threadIdx.x;
  const int wave = tid >> 6;
  const int lane = tid & 63;
  const int lr   = lane & 15;
  const int lq   = lane >> 4;
  const int row0 = blockIdx.x * 64;

  // stage enc_pos -> posb (cols 0..62 data, col 63 zero), swizzled
  for (int i = tid; i < 64 * 64; i += 256) {
    const int r = i >> 6, c = i & 63;
    const float v = (c < 63) ? enc_pos[(size_t)(row0 + r) * 63 + c] : 0.0f;
    *(unsigned short*)((char*)posb + (((r * 64 + c) << 1) ^ ((r & 7) << 4))) = f2bf(v);
  }
  __syncthreads();

  f32x4 acc[4][4];

  // L0: posb(K=64) -> act  (no pre-barrier: writes act, reads posb only)
  zero_acc(acc);
  gemm_frag<4, 4, 2, 16, 64>(acc, posb, 0, Wt + OFF_W0, wave * 4, 0);
  store_act<4, 4, true, 256>(acc, b0, wave * 64, act);
  __syncthreads();
  // L1
  zero_acc(acc);
  gemm_frag<4, 4, 8, 16, 256>(acc, act, 0, Wt + OFF_W1, wave * 4, 0);
  __syncthreads();
  store_act<4, 4, true, 256>(acc, b1, wave * 64, act);
  __syncthreads();
  // L2
  zero_acc(acc);
  gemm_frag<4, 4, 8, 16, 256>(acc, act, 0, Wt + OFF_W2, wave * 4, 0);
  __syncthreads();
  store_act<4, 4, true, 256>(acc, b2, wave * 64, act);
  __syncthreads();
  // L3
  zero_acc(acc);
  gemm_frag<4, 4, 8, 16, 256>(acc, act, 0, Wt + OFF_W3, wave * 4, 0);
  __syncthreads();
  store_act<4, 4, true, 256>(acc, b3, wave * 64, act);
  __syncthreads();
  // L4 (virtual skip concat): [act | posb], K = 256 + 64
  zero_acc(acc);
  gemm_frag<4, 4, 8, 16, 256>(acc, act, 0, Wt + OFF_W4, wave * 4, 0);
  gemm_frag<4, 4, 2, 16, 64>(acc, posb, 0, Wt + OFF_W4, wave * 4, 8);
  __syncthreads();
  store_act<4, 4, true, 256>(acc, b4, wave * 64, act);
  __syncthreads();
  // L5
  zero_acc(acc);
  gemm_frag<4, 4, 8, 16, 256>(acc, act, 0, Wt + OFF_W5, wave * 4, 0);
  __syncthreads();
  store_act<4, 4, true, 256>(acc, b5, wave * 64, act);
  __syncthreads();
  // L6
  zero_acc(acc);
  gemm_frag<4, 4, 8, 16, 256>(acc, act, 0, Wt + OFF_W6, wave * 4, 0);
  __syncthreads();
  store_act<4, 4, true, 256>(acc, b6, wave * 64, act);
  __syncthreads();
  // L7: act = h7 after this
  zero_acc(acc);
  gemm_frag<4, 4, 8, 16, 256>(acc, act, 0, Wt + OFF_W7, wave * 4, 0);
  __syncthreads();
  store_act<4, 4, true, 256>(acc, b7, wave * 64, act);
  __syncthreads();

  // stage enc_dir -> posb cols 0..31 (27 data + 5 zero); posb dead since L4.
  // Visibility to all waves is guaranteed by the post-feature-gemm barrier.
  for (int i = tid; i < 64 * 32; i += 256) {
    const int r = i >> 5, c = i & 31;
    const float v = (c < 27) ? enc_dir[(size_t)(row0 + r) * 27 + c] : 0.0f;
    *(unsigned short*)((char*)posb + (((r * 64 + c) << 1) ^ ((r & 7) << 4))) = f2bf(v);
  }

  // sigma = h7 @ Ws^T + bs (reads act only; writes global)
  {
    f32x4 sacc[1][1];
    zero_acc(sacc);
    gemm_frag<1, 1, 8, 1, 256>(sacc, act, wave * 16, Wt + OFF_WS, 0, 0);
    if (lr == 0) {
      const float bv = bsb[0];
      #pragma unroll
      for (int r = 0; r < 4; r++)
        out[(size_t)(row0 + wave * 16 + lq * 4 + r) * 4 + 3] = sacc[0][0][r] + bv;
    }
  }

  // feature = h7 @ Wf^T + bf (no relu), in-place into act
  zero_acc(acc);
  gemm_frag<4, 4, 8, 16, 256>(acc, act, 0, Wt + OFF_WF, wave * 4, 0);
  __syncthreads();   // all h7 reads (sigma+feature) done; dir staging done
  store_act<4, 4, false, 256>(acc, bfb, wave * 64, act);
  __syncthreads();

  // color_hidden = relu([feature | enc_dir] @ Wc1^T + bc1) -> act cols 0..127
  {
    f32x4 cacc[4][2];
    zero_acc(cacc);
    gemm_frag<4, 2, 8, 8, 256>(cacc, act, 0, Wt + OFF_WC1, wave * 2, 0);
    gemm_frag<4, 2, 1, 8, 64>(cacc, posb, 0, Wt + OFF_WC1, wave * 2, 8);
    __syncthreads();
    store_act<4, 2, true, 256>(cacc, bc1, wave * 32, act);
    __syncthreads();
  }

  // color_raw = color_hidden @ Wc2^T + bc2
  {
    f32x4 cacc[1][1];
    zero_acc(cacc);
    gemm_frag<1, 1, 4, 1, 256>(cacc, act, wave * 16, Wt + OFF_WC2, 0, 0);
    if (lr < 3) {
      const float bv = bc2[lr];
      #pragma unroll
      for (int r = 0; r < 4; r++)
        out[(size_t)(row0 + wave * 16 + lq * 4 + r) * 4 + lr] = cacc[0][0][r] + bv;
    }
  }
}

// ---------- launcher ----------
extern "C" void kernel_launch(void* const* d_in, const int* in_sizes, int n_in,
                              void* d_out, int out_size, void* d_ws, size_t ws_size,
                              hipStream_t stream) {
  const float* enc_pos = (const float*)d_in[0];
  const float* enc_dir = (const float*)d_in[1];
  unsigned short* wbf  = (unsigned short*)d_ws;

  SegArgs sa;
  sa.s[0]  = { (const float*)d_in[2],  256, 63,  16, 2,  OFF_W0  };
  sa.s[1]  = { (const float*)d_in[4],  256, 256, 16, 8,  OFF_W1  };
  sa.s[2]  = { (const float*)d_in[6],  256, 256, 16, 8,  OFF_W2  };
  sa.s[3]  = { (const float*)d_in[8],  256, 256, 16, 8,  OFF_W3  };
  sa.s[4]  = { (const float*)d_in[10], 256, 319, 16, 10, OFF_W4  };
  sa.s[5]  = { (const float*)d_in[12], 256, 256, 16, 8,  OFF_W5  };
  sa.s[6]  = { (const float*)d_in[14], 256, 256, 16, 8,  OFF_W6  };
  sa.s[7]  = { (const float*)d_in[16], 256, 256, 16, 8,  OFF_W7  };
  sa.s[8]  = { (const float*)d_in[18], 256, 256, 16, 8,  OFF_WF  };
  sa.s[9]  = { (const float*)d_in[22], 128, 283, 8,  9,  OFF_WC1 };
  sa.s[10] = { (const float*)d_in[20], 1,   256, 1,  8,  OFF_WS  };
  sa.s[11] = { (const float*)d_in[24], 3,   128, 1,  4,  OFF_WC2 };

  convert_weights<<<W_TOTAL / 256, 256, 0, stream>>>(sa, wbf);

  const int N = in_sizes[0] / 63;          // 524288
  const int blocks = N / 64;               // 8192
  nerf_main<<<blocks, 256, 0, stream>>>(
      enc_pos, enc_dir, wbf,
      (const float*)d_in[3],  (const float*)d_in[5],
      (const float*)d_in[7],  (const float*)d_in[9],
      (const float*)d_in[11], (const float*)d_in[13],
      (const float*)d_in[15], (const float*)d_in[17],
      (const float*)d_in[19], (const float*)d_in[21],
      (const float*)d_in[23], (const float*)d_in[25],
      (float*)d_out);
}

// Round 3
// 736.821 us; speedup vs baseline: 2.4826x; 2.4826x over previous
//
#include <hip/hip_runtime.h>
#include <hip/hip_bf16.h>

// ---------- types ----------
typedef __attribute__((ext_vector_type(8))) short bf16x8;   // 8 bf16 in 4 VGPRs
typedef __attribute__((ext_vector_type(4))) float f32x4;
typedef __attribute__((ext_vector_type(2))) unsigned int u32x2;

#define MFMA_BF16(a, b, c) __builtin_amdgcn_mfma_f32_16x16x32_bf16((a), (b), (c), 0, 0, 0)

static __device__ __forceinline__ unsigned short f2bf(float f) {
  unsigned int u = __builtin_bit_cast(unsigned int, f);
  u += 0x7FFF + ((u >> 16) & 1);   // RNE
  return (unsigned short)(u >> 16);
}
static __device__ __forceinline__ unsigned int pk2(float a, float b) {
  return (unsigned int)f2bf(a) | ((unsigned int)f2bf(b) << 16);
}

// ---------- weight layout in d_ws (bf16 elements), FRAGMENT-ORDERED ----------
// Each 512-elem (1KB) chunk is one MFMA fragment: elem = lane*8 + j holds
// W[nb*16 + (lane&15)][ks*32 + (lane>>4)*8 + j]. Chunk index = ks*NB + nb.
// Used as the A operand (m = output col). Identical lane layout to B.
enum : int {
  OFF_W0  = 0,        // NB=16 KS=2   (K 63 -> 64)
  OFF_W1  = 16384,    // NB=16 KS=8
  OFF_W2  = 81920,
  OFF_W3  = 147456,
  OFF_W4  = 212992,   // NB=16 KS=10  (K 319 -> 320)
  OFF_W5  = 294912,
  OFF_W6  = 360448,
  OFF_W7  = 425984,
  OFF_WF  = 491520,
  OFF_WC1 = 557056,   // NB=8  KS=9   (K 283 -> 288)
  OFF_WS  = 593920,   // NB=1  KS=8   (1 row -> 16)
  OFF_WC2 = 598016,   // NB=1  KS=4   (3 rows -> 16)
  W_TOTAL = 600064
};

struct Seg { const float* src; int rows_src, kin, nb, ks, off; };
struct SegArgs { Seg s[12]; };

__global__ void convert_weights(SegArgs args, unsigned short* __restrict__ dst) {
  int idx = blockIdx.x * 256 + threadIdx.x;
  #pragma unroll
  for (int i = 0; i < 12; i++) {
    const Seg sg = args.s[i];
    const int sz = sg.nb * sg.ks * 512;
    if (idx < sz) {
      const int f = idx >> 9, rm = idx & 511;
      const int lane = rm >> 3, j = rm & 7;
      const int ks = f / sg.nb, nb = f - ks * sg.nb;
      const int n = nb * 16 + (lane & 15);
      const int k = ks * 32 + ((lane >> 4) << 3) + j;
      float v = (n < sg.rows_src && k < sg.kin) ? sg.src[n * sg.kin + k] : 0.0f;
      dst[sg.off + idx] = f2bf(v);
      return;
    }
    idx -= sz;
  }
}

// ---------- GEMM helpers (SWAPPED operands) ----------
// MFMA 16x16x32 bf16: A and B inputs have identical lane layouts
//   (idx = lane&15, k = (lane>>4)*8 + j).  D[m][n]: n = lane&15, m = (lane>>4)*4+reg.
// We compute D = W-frag (A, m=outcol) x act-frag (B, n=row):
//   => lane holds row = lane&15, outcols = (lane>>4)*4 + 0..3  -> packed b64 stores.
// LDS act buffers XOR-swizzled: byte ^= (row&7)<<4 (bank-conflict-free for
// b128 reads and b64 stores; 2-way residual aliasing is free per m136).

template<int WF, int HF>
static __device__ __forceinline__ void zero_acc(f32x4 (&acc)[WF][HF]) {
  #pragma unroll
  for (int wf = 0; wf < WF; wf++)
    #pragma unroll
    for (int hf = 0; hf < HF; hf++)
      acc[wf][hf] = (f32x4){0.f, 0.f, 0.f, 0.f};
}

template<int WF, int HF>
static __device__ __forceinline__ void init_bias(
    f32x4 (&acc)[WF][HF], const float* __restrict__ bias, int colBase) {
  const int lq4 = ((threadIdx.x & 63) >> 4) * 4;
  #pragma unroll
  for (int wf = 0; wf < WF; wf++) {
    const f32x4 b = *(const f32x4*)(bias + colBase + wf * 16 + lq4);
    #pragma unroll
    for (int hf = 0; hf < HF; hf++) acc[wf][hf] = b;
  }
}

template<int WF, int HF, int KS, int NB, int ASTRIDE>
static __device__ __forceinline__ void gemm_frag(
    f32x4 (&acc)[WF][HF],
    const unsigned short* __restrict__ wseg, int nbBase, int ksOff,
    const unsigned short* __restrict__ aLds, int rowBase)
{
  const int lane = threadIdx.x & 63;
  const int lr   = lane & 15;
  const int lq8  = (lane >> 4) * 8;
  #pragma unroll 2
  for (int ks = 0; ks < KS; ks++) {
    bf16x8 w[WF], h[HF];
    #pragma unroll
    for (int wf = 0; wf < WF; wf++)
      w[wf] = *(const bf16x8*)(wseg + (((ksOff + ks) * NB + nbBase + wf) << 9) + lane * 8);
    #pragma unroll
    for (int hf = 0; hf < HF; hf++) {
      const int row = rowBase + hf * 16 + lr;
      const int col = ks * 32 + lq8;
      h[hf] = *(const bf16x8*)((const char*)aLds +
                (((row * ASTRIDE + col) << 1) ^ ((row & 7) << 4)));
    }
    #pragma unroll
    for (int wf = 0; wf < WF; wf++)
      #pragma unroll
      for (int hf = 0; hf < HF; hf++)
        acc[wf][hf] = MFMA_BF16(w[wf], h[hf], acc[wf][hf]);
  }
}

template<int WF, int HF, bool RELU, int ASTRIDE>
static __device__ __forceinline__ void store_act(
    const f32x4 (&acc)[WF][HF], int colBase, unsigned short* __restrict__ lds)
{
  const int lane = threadIdx.x & 63;
  const int lr   = lane & 15;
  const int lq4  = (lane >> 4) * 4;
  #pragma unroll
  for (int wf = 0; wf < WF; wf++) {
    const int col = colBase + wf * 16 + lq4;
    #pragma unroll
    for (int hf = 0; hf < HF; hf++) {
      const int row = hf * 16 + lr;
      f32x4 v = acc[wf][hf];
      if (RELU) {
        v[0] = fmaxf(v[0], 0.f); v[1] = fmaxf(v[1], 0.f);
        v[2] = fmaxf(v[2], 0.f); v[3] = fmaxf(v[3], 0.f);
      }
      u32x2 p; p[0] = pk2(v[0], v[1]); p[1] = pk2(v[2], v[3]);
      *(u32x2*)((char*)lds +
          (((row * ASTRIDE + col) << 1) ^ ((row & 7) << 4))) = p;
    }
  }
}

// ---------- fused NeRF kernel: 128 rows / block, 4 waves ----------
// Per wave: 128 rows x 64 cols (acc[4][8] = 128 VGPRs). Block N-split by wave.
__global__ __launch_bounds__(256, 2) void nerf_main(
    const float* __restrict__ enc_pos, const float* __restrict__ enc_dir,
    const unsigned short* __restrict__ Wt,
    const float* __restrict__ b0, const float* __restrict__ b1,
    const float* __restrict__ b2, const float* __restrict__ b3,
    const float* __restrict__ b4, const float* __restrict__ b5,
    const float* __restrict__ b6, const float* __restrict__ b7,
    const float* __restrict__ bfb, const float* __restrict__ bsb,
    const float* __restrict__ bc1, const float* __restrict__ bc2,
    float* __restrict__ out)
{
  __shared__ __align__(16) unsigned short act[128 * 256];   // 64 KB, swizzled
  __shared__ __align__(16) unsigned short posb[128 * 64];   // 16 KB, swizzled

  const int tid  = threadIdx.x;
  const int wave = tid >> 6;
  const int lane = tid & 63;
  const int lr   = lane & 15;
  const int lq   = lane >> 4;
  const int row0 = blockIdx.x * 128;

  // stage enc_pos -> posb (cols 0..62 data, col 63 zero), swizzled
  for (int i = tid; i < 128 * 64; i += 256) {
    const int r = i >> 6, c = i & 63;
    const float v = (c < 63) ? enc_pos[(size_t)(row0 + r) * 63 + c] : 0.0f;
    *(unsigned short*)((char*)posb + (((r * 64 + c) << 1) ^ ((r & 7) << 4))) = f2bf(v);
  }
  __syncthreads();

  f32x4 acc[4][8];

  // L0: posb (K=64) -> act
  init_bias<4, 8>(acc, b0, wave * 64);
  gemm_frag<4, 8, 2, 16, 64>(acc, Wt + OFF_W0, wave * 4, 0, posb, 0);
  store_act<4, 8, true, 256>(acc, wave * 64, act);
  __syncthreads();
  // L1
  init_bias<4, 8>(acc, b1, wave * 64);
  gemm_frag<4, 8, 8, 16, 256>(acc, Wt + OFF_W1, wave * 4, 0, act, 0);
  __syncthreads();
  store_act<4, 8, true, 256>(acc, wave * 64, act);
  __syncthreads();
  // L2
  init_bias<4, 8>(acc, b2, wave * 64);
  gemm_frag<4, 8, 8, 16, 256>(acc, Wt + OFF_W2, wave * 4, 0, act, 0);
  __syncthreads();
  store_act<4, 8, true, 256>(acc, wave * 64, act);
  __syncthreads();
  // L3
  init_bias<4, 8>(acc, b3, wave * 64);
  gemm_frag<4, 8, 8, 16, 256>(acc, Wt + OFF_W3, wave * 4, 0, act, 0);
  __syncthreads();
  store_act<4, 8, true, 256>(acc, wave * 64, act);
  __syncthreads();
  // L4 (virtual skip concat): [act | posb], K = 256 + 64
  init_bias<4, 8>(acc, b4, wave * 64);
  gemm_frag<4, 8, 8, 16, 256>(acc, Wt + OFF_W4, wave * 4, 0, act, 0);
  gemm_frag<4, 8, 2, 16, 64>(acc, Wt + OFF_W4, wave * 4, 8, posb, 0);
  __syncthreads();
  store_act<4, 8, true, 256>(acc, wave * 64, act);
  __syncthreads();
  // L5
  init_bias<4, 8>(acc, b5, wave * 64);
  gemm_frag<4, 8, 8, 16, 256>(acc, Wt + OFF_W5, wave * 4, 0, act, 0);
  __syncthreads();
  store_act<4, 8, true, 256>(acc, wave * 64, act);
  __syncthreads();
  // L6
  init_bias<4, 8>(acc, b6, wave * 64);
  gemm_frag<4, 8, 8, 16, 256>(acc, Wt + OFF_W6, wave * 4, 0, act, 0);
  __syncthreads();
  store_act<4, 8, true, 256>(acc, wave * 64, act);
  __syncthreads();
  // L7: act = h7 after this
  init_bias<4, 8>(acc, b7, wave * 64);
  gemm_frag<4, 8, 8, 16, 256>(acc, Wt + OFF_W7, wave * 4, 0, act, 0);
  __syncthreads();
  store_act<4, 8, true, 256>(acc, wave * 64, act);
  __syncthreads();

  // stage enc_dir -> posb cols 0..31 (27 data + 5 zero); posb dead since L4
  for (int i = tid; i < 128 * 32; i += 256) {
    const int r = i >> 5, c = i & 31;
    const float v = (c < 27) ? enc_dir[(size_t)(row0 + r) * 27 + c] : 0.0f;
    *(unsigned short*)((char*)posb + (((r * 64 + c) << 1) ^ ((r & 7) << 4))) = f2bf(v);
  }

  // sigma = h7 @ Ws^T + bs (rows split across waves; outcol 0 only)
  f32x4 sacc[1][2];
  zero_acc(sacc);
  gemm_frag<1, 2, 8, 1, 256>(sacc, Wt + OFF_WS, 0, 0, act, wave * 32);

  // feature = h7 @ Wf^T + bf (no relu), in-place into act
  init_bias<4, 8>(acc, bfb, wave * 64);
  gemm_frag<4, 8, 8, 16, 256>(acc, Wt + OFF_WF, wave * 4, 0, act, 0);
  __syncthreads();   // all h7 reads done (sigma + feature); dir staged
  store_act<4, 8, false, 256>(acc, wave * 64, act);
  // sigma store (global only, no LDS hazard)
  if (lq == 0) {
    const float bv = bsb[0];
    #pragma unroll
    for (int hf = 0; hf < 2; hf++)
      out[(size_t)(row0 + wave * 32 + hf * 16 + lr) * 4 + 3] = sacc[0][hf][0] + bv;
  }
  __syncthreads();

  // color_hidden = relu([feature | enc_dir] @ Wc1^T + bc1) -> act cols 0..127
  {
    f32x4 cacc[2][8];
    init_bias<2, 8>(cacc, bc1, wave * 32);
    gemm_frag<2, 8, 8, 8, 256>(cacc, Wt + OFF_WC1, wave * 2, 0, act, 0);
    gemm_frag<2, 8, 1, 8, 64>(cacc, Wt + OFF_WC1, wave * 2, 8, posb, 0);
    __syncthreads();
    store_act<2, 8, true, 256>(cacc, wave * 32, act);
    __syncthreads();
  }

  // color_raw = color_hidden @ Wc2^T + bc2 (outcols 0..2)
  {
    f32x4 c2[1][2];
    zero_acc(c2);
    gemm_frag<1, 2, 4, 1, 256>(c2, Wt + OFF_WC2, 0, 0, act, wave * 32);
    if (lq == 0) {
      #pragma unroll
      for (int hf = 0; hf < 2; hf++) {
        const size_t row = row0 + wave * 32 + hf * 16 + lr;
        #pragma unroll
        for (int r = 0; r < 3; r++)
          out[row * 4 + r] = c2[0][hf][r] + bc2[r];
      }
    }
  }
}

// ---------- launcher ----------
extern "C" void kernel_launch(void* const* d_in, const int* in_sizes, int n_in,
                              void* d_out, int out_size, void* d_ws, size_t ws_size,
                              hipStream_t stream) {
  const float* enc_pos = (const float*)d_in[0];
  const float* enc_dir = (const float*)d_in[1];
  unsigned short* wbf  = (unsigned short*)d_ws;

  SegArgs sa;
  sa.s[0]  = { (const float*)d_in[2],  256, 63,  16, 2,  OFF_W0  };
  sa.s[1]  = { (const float*)d_in[4],  256, 256, 16, 8,  OFF_W1  };
  sa.s[2]  = { (const float*)d_in[6],  256, 256, 16, 8,  OFF_W2  };
  sa.s[3]  = { (const float*)d_in[8],  256, 256, 16, 8,  OFF_W3  };
  sa.s[4]  = { (const float*)d_in[10], 256, 319, 16, 10, OFF_W4  };
  sa.s[5]  = { (const float*)d_in[12], 256, 256, 16, 8,  OFF_W5  };
  sa.s[6]  = { (const float*)d_in[14], 256, 256, 16, 8,  OFF_W6  };
  sa.s[7]  = { (const float*)d_in[16], 256, 256, 16, 8,  OFF_W7  };
  sa.s[8]  = { (const float*)d_in[18], 256, 256, 16, 8,  OFF_WF  };
  sa.s[9]  = { (const float*)d_in[22], 128, 283, 8,  9,  OFF_WC1 };
  sa.s[10] = { (const float*)d_in[20], 1,   256, 1,  8,  OFF_WS  };
  sa.s[11] = { (const float*)d_in[24], 3,   128, 1,  4,  OFF_WC2 };

  convert_weights<<<W_TOTAL / 256, 256, 0, stream>>>(sa, wbf);

  const int N = in_sizes[0] / 63;          // 524288
  const int blocks = N / 128;              // 4096
  nerf_main<<<blocks, 256, 0, stream>>>(
      enc_pos, enc_dir, wbf,
      (const float*)d_in[3],  (const float*)d_in[5],
      (const float*)d_in[7],  (const float*)d_in[9],
      (const float*)d_in[11], (const float*)d_in[13],
      (const float*)d_in[15], (const float*)d_in[17],
      (const float*)d_in[19], (const float*)d_in[21],
      (const float*)d_in[23], (const float*)d_in[25],
      (float*)d_out);
}